// Round 5
// baseline (210.881 us; speedup 1.0000x reference)
//
#include <hip/hip_runtime.h>

#define BLOCK    256
#define B_ROWS   131072
#define C_COLS   128
#define K_SEL    64
#define F4_PER_ROW (C_COLS / 4)                  // 32

// main kernel: 32 compacted rows per block, 4 (row,colquad) pairs per thread
#define ROWS_PB   32
#define GRID_MAIN (B_ROWS / ROWS_PB)             // 4096 (worst case all active)

// compact kernel: 1 row per thread
#define GRID_CMP  (B_ROWS / BLOCK)               // 512 (+1 block for w table)

// d_ws layout:
//   [0     ..   512) : float w[128]
//   [512   ..   516) : int   count (active rows)
//   [1024  .. 17408) : float partials[GRID_MAIN]
//   [65536 ..  +512K): int   rowids[B_ROWS]
#define WS_COUNT_OFF    512
#define WS_PARTIALS_OFF 1024
#define WS_ROWIDS_OFF   65536

__global__ void init_count(int* count) { *count = 0; }

__global__ void compact_and_w(const int* __restrict__ batch_mask,
                              const int* __restrict__ class_idx,
                              int* __restrict__ count,
                              int* __restrict__ rowids,
                              float* __restrict__ w)
{
    if (blockIdx.x == GRID_CMP) {        // last block builds the weight table
        if (threadIdx.x < C_COLS) {
            int c = threadIdx.x, cnt = 0;
            #pragma unroll
            for (int k = 0; k < K_SEL; ++k)
                cnt += (class_idx[k] == c) ? 1 : 0;
            w[c] = (float)cnt;
        }
        return;
    }
    const int row = blockIdx.x * BLOCK + threadIdx.x;
    const int m   = batch_mask[row] ? 1 : 0;
    const unsigned long long b = __ballot(m);
    const int lane   = threadIdx.x & 63;
    const int wcount = __popcll(b);
    const int prefix = __popcll(b & ((1ULL << lane) - 1ULL));
    int base = 0;
    if (lane == 0 && wcount) base = atomicAdd(count, wcount);
    base = __shfl(base, 0);
    if (m) rowids[base + prefix] = row;
}

__device__ __forceinline__ float fast_log(float x) {
    return __log2f(x) * 0.6931471805599453f;
}

__device__ __forceinline__ float per_elem_loss(float o, float oc, float y,
                                               float wc) {
    float sharp = (o > 0.5f) ? (o + (1.0f - o) * 0.25f)
                             : (o - o * 0.25f);
    float lo  = fmaxf(fast_log(o),        -100.0f);
    float l1o = fmaxf(fast_log(1.0f - o), -100.0f);
    float bce = -(y * lo + (1.0f - y) * l1o);
    float dp = o  - sharp;
    float dc = oc - sharp;
    return wc * (bce + dp * dp + dc * dc);
}

__global__ __launch_bounds__(BLOCK, 4) void semi_loss_main(
    const float* __restrict__ out,
    const float* __restrict__ outc,
    const float* __restrict__ lab,
    const int*  __restrict__ count,
    const int*  __restrict__ rowids,
    const float* __restrict__ wtab,
    float* __restrict__ partials)
{
    const int nact = *count;
    const int base = blockIdx.x * ROWS_PB;

    if (base >= nact) {                       // no work: publish zero partial
        if (threadIdx.x == 0) partials[blockIdx.x] = 0.0f;
        return;
    }

    __shared__ int   srow[ROWS_PB];
    __shared__ float sval[ROWS_PB];
    if (threadIdx.x < ROWS_PB) {
        int idx = base + threadIdx.x;
        srow[threadIdx.x] = (idx < nact) ? rowids[idx] : rowids[base];
        sval[threadIdx.x] = (idx < nact) ? 1.0f : 0.0f;
    }
    const int cq = threadIdx.x & 31;          // col-quad, constant per thread
    const float4 w4 = ((const float4*)wtab)[cq];
    __syncthreads();

    const int lr0 = threadIdx.x >> 5;         // 0..7

    // Gather the 4 (row, valid) pairs, compute addresses, then issue all
    // 12 float4 loads back-to-back before any use.
    int   v[4];
    float val[4];
    #pragma unroll
    for (int i = 0; i < 4; ++i) {
        int lr = lr0 + 8 * i;
        v[i]   = srow[lr] * F4_PER_ROW + cq;
        val[i] = sval[lr];
    }

    float4 o4[4], oc4[4], y4[4];
    #pragma unroll
    for (int i = 0; i < 4; ++i) {
        o4[i]  = ((const float4*)out )[v[i]];
        oc4[i] = ((const float4*)outc)[v[i]];
        y4[i]  = ((const float4*)lab )[v[i]];
    }

    float sum = 0.0f;
    #pragma unroll
    for (int i = 0; i < 4; ++i) {
        float s = per_elem_loss(o4[i].x, oc4[i].x, y4[i].x, w4.x)
                + per_elem_loss(o4[i].y, oc4[i].y, y4[i].y, w4.y)
                + per_elem_loss(o4[i].z, oc4[i].z, y4[i].z, w4.z)
                + per_elem_loss(o4[i].w, oc4[i].w, y4[i].w, w4.w);
        sum += val[i] * s;
    }

    #pragma unroll
    for (int off = 32; off > 0; off >>= 1)
        sum += __shfl_down(sum, off);

    __shared__ float ssum[BLOCK / 64];
    int wave = threadIdx.x >> 6;
    int lane = threadIdx.x & 63;
    if (lane == 0) ssum[wave] = sum;
    __syncthreads();
    if (threadIdx.x == 0) {
        float s = 0.0f;
        #pragma unroll
        for (int i = 0; i < BLOCK / 64; ++i) s += ssum[i];
        partials[blockIdx.x] = s;
    }
}

__global__ __launch_bounds__(BLOCK) void semi_loss_reduce(
    const float* __restrict__ partials,
    const int*  __restrict__ count,
    float* __restrict__ outv)
{
    double s = 0.0;
    for (int i = threadIdx.x; i < GRID_MAIN; i += BLOCK)
        s += (double)partials[i];
    #pragma unroll
    for (int off = 32; off > 0; off >>= 1)
        s += __shfl_down(s, off);
    __shared__ double dsum[BLOCK / 64];
    int wave = threadIdx.x >> 6;
    int lane = threadIdx.x & 63;
    if (lane == 0) dsum[wave] = s;
    __syncthreads();
    if (threadIdx.x == 0) {
        double ts = 0.0;
        #pragma unroll
        for (int i = 0; i < BLOCK / 64; ++i) ts += dsum[i];
        int n = *count;
        outv[0] = (n > 0) ? (float)(ts / ((double)n * (double)K_SEL)) : 0.0f;
    }
}

extern "C" void kernel_launch(void* const* d_in, const int* in_sizes, int n_in,
                              void* d_out, int out_size, void* d_ws, size_t ws_size,
                              hipStream_t stream) {
    const float* out_p  = (const float*)d_in[0];
    const float* outc_p = (const float*)d_in[1];
    const float* lab_p  = (const float*)d_in[2];
    const int*   cidx_p = (const int*)d_in[3];
    const int*   mask_p = (const int*)d_in[4];

    float* wtab     = (float*)d_ws;
    int*   count    = (int*)((char*)d_ws + WS_COUNT_OFF);
    float* partials = (float*)((char*)d_ws + WS_PARTIALS_OFF);
    int*   rowids   = (int*)((char*)d_ws + WS_ROWIDS_OFF);

    init_count<<<1, 1, 0, stream>>>(count);
    compact_and_w<<<GRID_CMP + 1, BLOCK, 0, stream>>>(mask_p, cidx_p,
                                                      count, rowids, wtab);
    semi_loss_main<<<GRID_MAIN, BLOCK, 0, stream>>>(out_p, outc_p, lab_p,
                                                    count, rowids, wtab,
                                                    partials);
    semi_loss_reduce<<<1, BLOCK, 0, stream>>>(partials, count, (float*)d_out);
}

// Round 6
// 210.648 us; speedup vs baseline: 1.0011x; 1.0011x over previous
//
#include <hip/hip_runtime.h>

#define BLOCK    256
#define B_ROWS   131072
#define C_COLS   128
#define K_SEL    64
#define F4_PER_ROW (C_COLS / 4)                  // 32

// main kernel: 32 compacted rows per block, 4 (row,colquad) pairs per thread
#define ROWS_PB   32
#define GRID_MAIN (B_ROWS / ROWS_PB)             // 4096 (worst case all active)

// compact kernel: 1 row per thread
#define GRID_CMP  (B_ROWS / BLOCK)               // 512 (+1 block for w table)

// d_ws layout:
//   [0     ..   512) : float w[128]
//   [512   ..   516) : int   count (active rows)
//   [1024  .. 17408) : float partials[GRID_MAIN]
//   [65536 ..  +512K): int   rowids[B_ROWS]
#define WS_COUNT_OFF    512
#define WS_PARTIALS_OFF 1024
#define WS_ROWIDS_OFF   65536

__global__ void compact_and_w(const int* __restrict__ batch_mask,
                              const int* __restrict__ class_idx,
                              int* __restrict__ count,
                              int* __restrict__ rowids,
                              float* __restrict__ w)
{
    if (blockIdx.x == GRID_CMP) {        // last block builds the weight table
        if (threadIdx.x < C_COLS) {
            int c = threadIdx.x, cnt = 0;
            #pragma unroll
            for (int k = 0; k < K_SEL; ++k)
                cnt += (class_idx[k] == c) ? 1 : 0;
            w[c] = (float)cnt;
        }
        return;
    }
    const int row = blockIdx.x * BLOCK + threadIdx.x;
    const int m   = batch_mask[row] ? 1 : 0;
    const unsigned long long b = __ballot(m);
    const int lane   = threadIdx.x & 63;
    const int wcount = __popcll(b);
    const int prefix = __popcll(b & ((1ULL << lane) - 1ULL));
    int base = 0;
    if (lane == 0 && wcount) base = atomicAdd(count, wcount);
    base = __shfl(base, 0);
    if (m) rowids[base + prefix] = row;
}

__device__ __forceinline__ float fast_log(float x) {
    return __log2f(x) * 0.6931471805599453f;
}

__device__ __forceinline__ float per_elem_loss(float o, float oc, float y,
                                               float wc) {
    float sharp = (o > 0.5f) ? (o + (1.0f - o) * 0.25f)
                             : (o - o * 0.25f);
    float lo  = fmaxf(fast_log(o),        -100.0f);
    float l1o = fmaxf(fast_log(1.0f - o), -100.0f);
    float bce = -(y * lo + (1.0f - y) * l1o);
    float dp = o  - sharp;
    float dc = oc - sharp;
    return wc * (bce + dp * dp + dc * dc);
}

__global__ __launch_bounds__(BLOCK, 4) void semi_loss_main(
    const float* __restrict__ out,
    const float* __restrict__ outc,
    const float* __restrict__ lab,
    const int*  __restrict__ count,
    const int*  __restrict__ rowids,
    const float* __restrict__ wtab,
    float* __restrict__ partials)
{
    const int nact = *count;
    const int base = blockIdx.x * ROWS_PB;

    if (base >= nact) {                       // no work: publish zero partial
        if (threadIdx.x == 0) partials[blockIdx.x] = 0.0f;
        return;
    }

    __shared__ int   srow[ROWS_PB];
    __shared__ float sval[ROWS_PB];
    if (threadIdx.x < ROWS_PB) {
        int idx = base + threadIdx.x;
        srow[threadIdx.x] = (idx < nact) ? rowids[idx] : rowids[base];
        sval[threadIdx.x] = (idx < nact) ? 1.0f : 0.0f;
    }
    const int cq = threadIdx.x & 31;          // col-quad, constant per thread
    const float4 w4 = ((const float4*)wtab)[cq];
    __syncthreads();

    const int lr0 = threadIdx.x >> 5;         // 0..7

    int   v[4];
    float val[4];
    #pragma unroll
    for (int i = 0; i < 4; ++i) {
        int lr = lr0 + 8 * i;
        v[i]   = srow[lr] * F4_PER_ROW + cq;
        val[i] = sval[lr];
    }

    // Issue all 12 float4 loads, then FORCE them to stay clustered:
    // sched_barrier(0) forbids the scheduler from sinking any load past it,
    // so all 12 global_load_dwordx4 remain in flight simultaneously.
    float4 o4[4], oc4[4], y4[4];
    #pragma unroll
    for (int i = 0; i < 4; ++i) o4[i]  = ((const float4*)out )[v[i]];
    #pragma unroll
    for (int i = 0; i < 4; ++i) oc4[i] = ((const float4*)outc)[v[i]];
    #pragma unroll
    for (int i = 0; i < 4; ++i) y4[i]  = ((const float4*)lab )[v[i]];
    __builtin_amdgcn_sched_barrier(0);

    float sum = 0.0f;
    #pragma unroll
    for (int i = 0; i < 4; ++i) {
        float s = per_elem_loss(o4[i].x, oc4[i].x, y4[i].x, w4.x)
                + per_elem_loss(o4[i].y, oc4[i].y, y4[i].y, w4.y)
                + per_elem_loss(o4[i].z, oc4[i].z, y4[i].z, w4.z)
                + per_elem_loss(o4[i].w, oc4[i].w, y4[i].w, w4.w);
        sum += val[i] * s;
    }

    #pragma unroll
    for (int off = 32; off > 0; off >>= 1)
        sum += __shfl_down(sum, off);

    __shared__ float ssum[BLOCK / 64];
    int wave = threadIdx.x >> 6;
    int lane = threadIdx.x & 63;
    if (lane == 0) ssum[wave] = sum;
    __syncthreads();
    if (threadIdx.x == 0) {
        float s = 0.0f;
        #pragma unroll
        for (int i = 0; i < BLOCK / 64; ++i) s += ssum[i];
        partials[blockIdx.x] = s;
    }
}

__global__ __launch_bounds__(BLOCK) void semi_loss_reduce(
    const float* __restrict__ partials,
    const int*  __restrict__ count,
    float* __restrict__ outv)
{
    double s = 0.0;
    for (int i = threadIdx.x; i < GRID_MAIN; i += BLOCK)
        s += (double)partials[i];
    #pragma unroll
    for (int off = 32; off > 0; off >>= 1)
        s += __shfl_down(s, off);
    __shared__ double dsum[BLOCK / 64];
    int wave = threadIdx.x >> 6;
    int lane = threadIdx.x & 63;
    if (lane == 0) dsum[wave] = s;
    __syncthreads();
    if (threadIdx.x == 0) {
        double ts = 0.0;
        #pragma unroll
        for (int i = 0; i < BLOCK / 64; ++i) ts += dsum[i];
        int n = *count;
        outv[0] = (n > 0) ? (float)(ts / ((double)n * (double)K_SEL)) : 0.0f;
    }
}

extern "C" void kernel_launch(void* const* d_in, const int* in_sizes, int n_in,
                              void* d_out, int out_size, void* d_ws, size_t ws_size,
                              hipStream_t stream) {
    const float* out_p  = (const float*)d_in[0];
    const float* outc_p = (const float*)d_in[1];
    const float* lab_p  = (const float*)d_in[2];
    const int*   cidx_p = (const int*)d_in[3];
    const int*   mask_p = (const int*)d_in[4];

    float* wtab     = (float*)d_ws;
    int*   count    = (int*)((char*)d_ws + WS_COUNT_OFF);
    float* partials = (float*)((char*)d_ws + WS_PARTIALS_OFF);
    int*   rowids   = (int*)((char*)d_ws + WS_ROWIDS_OFF);

    hipMemsetAsync(count, 0, sizeof(int), stream);
    compact_and_w<<<GRID_CMP + 1, BLOCK, 0, stream>>>(mask_p, cidx_p,
                                                      count, rowids, wtab);
    semi_loss_main<<<GRID_MAIN, BLOCK, 0, stream>>>(out_p, outc_p, lab_p,
                                                    count, rowids, wtab,
                                                    partials);
    semi_loss_reduce<<<1, BLOCK, 0, stream>>>(partials, count, (float*)d_out);
}